// Round 1
// baseline (493.115 us; speedup 1.0000x reference)
//
#include <hip/hip_runtime.h>

typedef unsigned int uint;
typedef unsigned short ushort;
typedef __bf16 bf16x8 __attribute__((ext_vector_type(8)));
typedef float f32x4 __attribute__((ext_vector_type(4)));

#define L2E 1.44269504088896340736f

__device__ __forceinline__ ushort f2bf(float f) {
  union { float f; uint u; } c; c.f = f;
  uint u = c.u + 0x7fffu + ((c.u >> 16) & 1u);
  return (ushort)(u >> 16);
}
__device__ __forceinline__ float bflo(uint u) { union { uint u; float f; } c; c.u = u << 16; return c.f; }
__device__ __forceinline__ float bfhi(uint u) { union { uint u; float f; } c; c.u = u & 0xffff0000u; return c.f; }

__device__ __forceinline__ void gload16(const void* g, void* l) {
  __builtin_amdgcn_global_load_lds((const __attribute__((address_space(1))) void*)g,
                                   (__attribute__((address_space(3))) void*)l, 16, 0, 0);
}

// ---------------- cast + transpose: x [B][C][4096] f32 -> xt [B][4096][C] bf16 ----------------
__global__ void cast_transpose(const float* __restrict__ x, ushort* __restrict__ xt) {
  __shared__ float t[32][33];
  const int b = blockIdx.z, pc = blockIdx.x, cc = blockIdx.y;
  const int tx = threadIdx.x, ty = threadIdx.y; // 32 x 8
  const float* xb = x + ((size_t)b * 256 + cc * 32) * 4096 + pc * 32;
#pragma unroll
  for (int i = 0; i < 4; ++i)
    t[ty * 4 + i][tx] = xb[(size_t)(ty * 4 + i) * 4096 + tx];
  __syncthreads();
  ushort* xtb = xt + ((size_t)b * 4096 + pc * 32) * 256 + cc * 32;
#pragma unroll
  for (int i = 0; i < 4; ++i)
    xtb[(size_t)(ty * 4 + i) * 256 + tx] = f2bf(t[tx][ty * 4 + i]);
}

// ---------------- elementwise f32 -> bf16 with scale ----------------
__global__ void cast_scale(const float* __restrict__ src, ushort* __restrict__ dst, int n, float scale) {
  int i = blockIdx.x * 256 + threadIdx.x;
  if (i < n) dst[i] = f2bf(src[i] * scale);
}

// ---------------- GroupNorm on pixel-major bf16 [B][4096][256], G=32 (8 ch/group) ----------------
__global__ void groupnorm(const ushort* __restrict__ y, ushort* __restrict__ gout,
                          const float* __restrict__ gamma, const float* __restrict__ beta) {
  const int g = blockIdx.x, b = blockIdx.y;
  const int tid = threadIdx.x; // 256
  const size_t base = ((size_t)b * 4096) * 256 + g * 8;
  float s = 0.f, ss = 0.f;
#pragma unroll
  for (int i = 0; i < 16; ++i) {
    int p = i * 256 + tid;
    uint4 raw = *(const uint4*)(y + base + (size_t)p * 256);
    float v0 = bflo(raw.x), v1 = bfhi(raw.x), v2 = bflo(raw.y), v3 = bfhi(raw.y);
    float v4 = bflo(raw.z), v5 = bfhi(raw.z), v6 = bflo(raw.w), v7 = bfhi(raw.w);
    s += v0 + v1 + v2 + v3 + v4 + v5 + v6 + v7;
    ss += v0 * v0 + v1 * v1 + v2 * v2 + v3 * v3 + v4 * v4 + v5 * v5 + v6 * v6 + v7 * v7;
  }
#pragma unroll
  for (int off = 1; off < 64; off <<= 1) { s += __shfl_xor(s, off); ss += __shfl_xor(ss, off); }
  __shared__ float red[10];
  if ((tid & 63) == 0) { red[tid >> 6] = s; red[4 + (tid >> 6)] = ss; }
  __syncthreads();
  if (tid == 0) {
    float S = red[0] + red[1] + red[2] + red[3];
    float SS = red[4] + red[5] + red[6] + red[7];
    float mu = S * (1.f / 32768.f);
    float var = SS * (1.f / 32768.f) - mu * mu;
    red[8] = mu; red[9] = rsqrtf(var + 1e-5f);
  }
  __syncthreads();
  const float mu = red[8], rstd = red[9];
  float ga[8], be[8];
#pragma unroll
  for (int j = 0; j < 8; ++j) { ga[j] = gamma[g * 8 + j]; be[j] = beta[g * 8 + j]; }
#pragma unroll
  for (int i = 0; i < 16; ++i) {
    int p = i * 256 + tid;
    const size_t off = base + (size_t)p * 256;
    uint4 raw = *(const uint4*)(y + off);
    float v[8] = { bflo(raw.x), bfhi(raw.x), bflo(raw.y), bfhi(raw.y),
                   bflo(raw.z), bfhi(raw.z), bflo(raw.w), bfhi(raw.w) };
    ushort o[8];
#pragma unroll
    for (int j = 0; j < 8; ++j) o[j] = f2bf((v[j] - mu) * rstd * ga[j] + be[j]);
    uint4 w;
    w.x = (uint)o[0] | ((uint)o[1] << 16); w.y = (uint)o[2] | ((uint)o[3] << 16);
    w.z = (uint)o[4] | ((uint)o[5] << 16); w.w = (uint)o[6] | ((uint)o[7] << 16);
    *(uint4*)(gout + off) = w;
  }
}

// ---------------- GEMM: D[p][o] = sum_c A[b][p][c] * W[o][c] (+bias), optional 2nd pair ----------------
// out_pm: bf16 [b][4096][pm_stride] for o<split ; out_cm: bf16 [b][Cout-split][4096] for o>=split ;
// out_f32: f32 [b][Cout][4096]
__launch_bounds__(256)
__global__ void gemm_bt(const ushort* __restrict__ A, const ushort* __restrict__ A2,
                        const ushort* __restrict__ W, const ushort* __restrict__ W2,
                        const float* __restrict__ bias, const float* __restrict__ bias2,
                        ushort* __restrict__ out_pm, int pm_stride,
                        ushort* __restrict__ out_cm, float* __restrict__ out_f32,
                        int Cout, int split) {
  __shared__ ushort a_lds[128 * 64];
  __shared__ ushort b_lds[64 * 64];
  const int b = blockIdx.z;
  const int m0 = blockIdx.y * 128;
  const int n0 = blockIdx.x * 64;
  const int tid = threadIdx.x;
  const int w = tid >> 6, l = tid & 63;
  const int wr = w >> 1, wc = w & 1;
  const int lr = l & 15, lg = l >> 4;

  f32x4 acc[4][2] = {};
  const int npass = A2 ? 2 : 1;
  for (int pass = 0; pass < npass; ++pass) {
    const ushort* Ap = (pass ? A2 : A) + (size_t)b * 4096 * 256;
    const ushort* Wp = (pass ? W2 : W);
    for (int ko = 0; ko < 256; ko += 64) {
      __syncthreads();
      // stage A tile [128][64]
#pragma unroll
      for (int j = 0; j < 4; ++j) {
        int cb = (j * 4 + w) * 64;
        int chunk = cb + l;
        int row = chunk >> 3, ce = (chunk & 7) * 8;
        gload16(Ap + (size_t)(m0 + row) * 256 + ko + ce, &a_lds[cb * 8]);
      }
      // stage Bt tile [64][64]
#pragma unroll
      for (int j = 0; j < 2; ++j) {
        int cb = (j * 4 + w) * 64;
        int chunk = cb + l;
        int row = chunk >> 3, ce = (chunk & 7) * 8;
        gload16(Wp + (size_t)(n0 + row) * 256 + ko + ce, &b_lds[cb * 8]);
      }
      __syncthreads();
#pragma unroll
      for (int kk = 0; kk < 2; ++kk) {
        bf16x8 af[4], bfr[2];
#pragma unroll
        for (int m = 0; m < 4; ++m)
          af[m] = *(const bf16x8*)&a_lds[(wr * 64 + m * 16 + lr) * 64 + kk * 32 + lg * 8];
#pragma unroll
        for (int n = 0; n < 2; ++n)
          bfr[n] = *(const bf16x8*)&b_lds[(wc * 32 + n * 16 + lr) * 64 + kk * 32 + lg * 8];
#pragma unroll
        for (int m = 0; m < 4; ++m)
#pragma unroll
          for (int n = 0; n < 2; ++n)
            acc[m][n] = __builtin_amdgcn_mfma_f32_16x16x32_bf16(af[m], bfr[n], acc[m][n], 0, 0, 0);
      }
    }
  }
#pragma unroll
  for (int n = 0; n < 2; ++n) {
    int o = n0 + wc * 32 + n * 16 + lr;
    float bv = 0.f;
    if (bias) bv += bias[o];
    if (bias2) bv += bias2[o];
#pragma unroll
    for (int m = 0; m < 4; ++m) {
      int p0 = m0 + wr * 64 + m * 16 + lg * 4;
      f32x4 v = acc[m][n];
#pragma unroll
      for (int r = 0; r < 4; ++r) {
        float val = v[r] + bv;
        int p = p0 + r;
        if (out_pm && o < split) out_pm[((size_t)b * 4096 + p) * pm_stride + o] = f2bf(val);
        if (out_cm && o >= split) out_cm[((size_t)b * (Cout - split) + (o - split)) * 4096 + p] = f2bf(val);
        if (out_f32) out_f32[((size_t)b * Cout + o) * 4096 + p] = val;
      }
    }
  }
}

// ---------------- flash attention: Q [B][4096][256] (pre-scaled), K [B][4096][256], V [B][256][4096]
// O [B][4096][256] bf16 pixel-major. Q-tile 64 (wave w owns 16 q rows), K-tile 64.
__launch_bounds__(256)
__global__ void attn(const ushort* __restrict__ Q, const ushort* __restrict__ K,
                     const ushort* __restrict__ V, ushort* __restrict__ O) {
  __shared__ ushort q_lds[64 * 256];
  __shared__ ushort k_lds[64 * 256];
  __shared__ ushort v_lds[256 * 64];
  __shared__ ushort p_lds[4 * 16 * 64];
  const int b = blockIdx.y, qt = blockIdx.x;
  const int tid = threadIdx.x;
  const int w = tid >> 6, l = tid & 63;
  const int lr = l & 15, lg = l >> 4;

  const ushort* Qb = Q + (size_t)b * 4096 * 256;
  const ushort* Kb = K + (size_t)b * 4096 * 256;
  const ushort* Vb = V + (size_t)b * 256 * 4096;

  // stage Q tile [64][256]
#pragma unroll
  for (int j = 0; j < 8; ++j) {
    int cb = (j * 4 + w) * 64;
    int chunk = cb + l;
    int row = chunk >> 5, ce = (chunk & 31) * 8;
    gload16(Qb + (size_t)(qt * 64 + row) * 256 + ce, &q_lds[cb * 8]);
  }

  float mrow[4], lsum[4];
#pragma unroll
  for (int r = 0; r < 4; ++r) { mrow[r] = -1e30f; lsum[r] = 0.f; }
  f32x4 oacc[16] = {};

  for (int kt = 0; kt < 64; ++kt) {
    __syncthreads();
    // stage K tile [64][256] (pixel-major)
#pragma unroll
    for (int j = 0; j < 8; ++j) {
      int cb = (j * 4 + w) * 64;
      int chunk = cb + l;
      int row = chunk >> 5, ce = (chunk & 31) * 8;
      gload16(Kb + (size_t)(kt * 64 + row) * 256 + ce, &k_lds[cb * 8]);
    }
    // stage V tile [256][64] (channel-major)
#pragma unroll
    for (int j = 0; j < 8; ++j) {
      int cb = (j * 4 + w) * 64;
      int chunk = cb + l;
      int row = chunk >> 3, ce = (chunk & 7) * 8;
      gload16(Vb + (size_t)row * 4096 + kt * 64 + ce, &v_lds[cb * 8]);
    }
    __syncthreads();

    // S = Q * K^T for this wave's 16 q rows x 64 k cols
    f32x4 s[4] = {};
#pragma unroll
    for (int kk = 0; kk < 8; ++kk) {
      bf16x8 a = *(const bf16x8*)&q_lds[(w * 16 + lr) * 256 + kk * 32 + lg * 8];
#pragma unroll
      for (int n = 0; n < 4; ++n) {
        bf16x8 bb = *(const bf16x8*)&k_lds[(n * 16 + lr) * 256 + kk * 32 + lg * 8];
        s[n] = __builtin_amdgcn_mfma_f32_16x16x32_bf16(a, bb, s[n], 0, 0, 0);
      }
    }

    // online softmax
    float p[4][4];
#pragma unroll
    for (int r = 0; r < 4; ++r) {
      float tm = fmaxf(fmaxf(s[0][r], s[1][r]), fmaxf(s[2][r], s[3][r]));
      tm = fmaxf(tm, __shfl_xor(tm, 1, 16));
      tm = fmaxf(tm, __shfl_xor(tm, 2, 16));
      tm = fmaxf(tm, __shfl_xor(tm, 4, 16));
      tm = fmaxf(tm, __shfl_xor(tm, 8, 16));
      float mn = fmaxf(mrow[r], tm);
      float alpha = exp2f((mrow[r] - mn) * L2E);
      float rs = 0.f;
#pragma unroll
      for (int n = 0; n < 4; ++n) { p[n][r] = exp2f((s[n][r] - mn) * L2E); rs += p[n][r]; }
      rs += __shfl_xor(rs, 1, 16);
      rs += __shfl_xor(rs, 2, 16);
      rs += __shfl_xor(rs, 4, 16);
      rs += __shfl_xor(rs, 8, 16);
      lsum[r] = lsum[r] * alpha + rs;
      mrow[r] = mn;
#pragma unroll
      for (int nf = 0; nf < 16; ++nf) oacc[nf][r] *= alpha;
    }
    // P -> LDS (per-wave slice), C/D layout -> A layout bounce
#pragma unroll
    for (int n = 0; n < 4; ++n)
#pragma unroll
      for (int r = 0; r < 4; ++r)
        p_lds[(w * 16 + lg * 4 + r) * 64 + n * 16 + lr] = f2bf(p[n][r]);

    // O += P * V
#pragma unroll
    for (int ks = 0; ks < 2; ++ks) {
      bf16x8 pa = *(const bf16x8*)&p_lds[(w * 16 + lr) * 64 + ks * 32 + lg * 8];
#pragma unroll
      for (int nf = 0; nf < 16; ++nf) {
        bf16x8 vb = *(const bf16x8*)&v_lds[(nf * 16 + lr) * 64 + ks * 32 + lg * 8];
        oacc[nf] = __builtin_amdgcn_mfma_f32_16x16x32_bf16(pa, vb, oacc[nf], 0, 0, 0);
      }
    }
  }

  ushort* Ob = O + (size_t)b * 4096 * 256;
#pragma unroll
  for (int nf = 0; nf < 16; ++nf) {
#pragma unroll
    for (int r = 0; r < 4; ++r) {
      int qp = qt * 64 + w * 16 + lg * 4 + r;
      Ob[(size_t)qp * 256 + nf * 16 + lr] = f2bf(oacc[nf][r] / lsum[r]);
    }
  }
}

extern "C" void kernel_launch(void* const* d_in, const int* in_sizes, int n_in,
                              void* d_out, int out_size, void* d_ws, size_t ws_size,
                              hipStream_t stream) {
  const float* x1 = (const float*)d_in[0];
  const float* x2 = (const float*)d_in[1];
  const float* w1 = (const float*)d_in[2];
  const float* b1 = (const float*)d_in[3];
  const float* w2 = (const float*)d_in[4];
  const float* b2 = (const float*)d_in[5];
  const float* gn_w = (const float*)d_in[6];
  const float* gn_b = (const float*)d_in[7];
  const float* wqkv = (const float*)d_in[8];
  const float* wout = (const float*)d_in[9];
  const float* bout = (const float*)d_in[10];
  const float* wsk = (const float*)d_in[11];
  const float* bsk = (const float*)d_in[12];
  float* out = (float*)d_out;

  const size_t NB = (size_t)4 * 4096 * 256; // elems per big bf16 buffer
  ushort* x1t = (ushort*)d_ws;      // later reused as q1t
  ushort* x2t = x1t + NB;           // later reused as k2t
  ushort* y1t = x2t + NB;           // persists (skip input)
  ushort* y2t = y1t + NB;           // GN'd in place -> g2t
  ushort* g1t = y2t + NB;           // later reused as ot
  ushort* v2  = g1t + NB;
  ushort* w1b = v2 + NB;
  ushort* w2b = w1b + 65536;
  ushort* wqb = w2b + 65536;
  ushort* wkvb = wqb + 65536;       // 131072
  ushort* woutb = wkvb + 131072;
  ushort* wskb = woutb + 65536;

  dim3 tb(32, 8);
  cast_transpose<<<dim3(128, 8, 4), tb, 0, stream>>>(x1, x1t);
  cast_transpose<<<dim3(128, 8, 4), tb, 0, stream>>>(x2, x2t);
  cast_scale<<<256, 256, 0, stream>>>(w1, w1b, 65536, 1.f);
  cast_scale<<<256, 256, 0, stream>>>(w2, w2b, 65536, 1.f);
  cast_scale<<<256, 256, 0, stream>>>(wqkv, wqb, 65536, 0.0625f); // fold 1/sqrt(256)
  cast_scale<<<512, 256, 0, stream>>>(wqkv + 65536, wkvb, 131072, 1.f);
  cast_scale<<<256, 256, 0, stream>>>(wout, woutb, 65536, 1.f);
  cast_scale<<<256, 256, 0, stream>>>(wsk, wskb, 65536, 1.f);

  // x1 = conv(x1,w1)+b1 ; x2 = conv(x2,w2)+b2
  gemm_bt<<<dim3(4, 32, 4), 256, 0, stream>>>(x1t, nullptr, w1b, nullptr, b1, nullptr,
                                              y1t, 256, nullptr, nullptr, 256, 256);
  gemm_bt<<<dim3(4, 32, 4), 256, 0, stream>>>(x2t, nullptr, w2b, nullptr, b2, nullptr,
                                              y2t, 256, nullptr, nullptr, 256, 256);
  // group norms (second one in place)
  groupnorm<<<dim3(32, 4), 256, 0, stream>>>(y1t, g1t, gn_w, gn_b);
  groupnorm<<<dim3(32, 4), 256, 0, stream>>>(y2t, y2t, gn_w, gn_b);
  // q1 = g1 @ wq^T (pre-scaled) ; [k2|v2] = g2 @ wkv^T
  gemm_bt<<<dim3(4, 32, 4), 256, 0, stream>>>(g1t, nullptr, wqb, nullptr, nullptr, nullptr,
                                              x1t, 256, nullptr, nullptr, 256, 256);
  gemm_bt<<<dim3(8, 32, 4), 256, 0, stream>>>(y2t, nullptr, wkvb, nullptr, nullptr, nullptr,
                                              x2t, 256, v2, nullptr, 512, 256);
  // attention
  attn<<<dim3(64, 4), 256, 0, stream>>>(x1t, x2t, v2, g1t);
  // out = ot @ wout^T + bout + y1 @ wsk^T + bsk  (fp32 channel-major to d_out)
  gemm_bt<<<dim3(4, 32, 4), 256, 0, stream>>>(g1t, y1t, woutb, wskb, bout, bsk,
                                              nullptr, 0, nullptr, out, 256, 0);
}

// Round 2
// 364.645 us; speedup vs baseline: 1.3523x; 1.3523x over previous
//
#include <hip/hip_runtime.h>

typedef unsigned int uint;
typedef unsigned short ushort;
typedef __bf16 bf16x8 __attribute__((ext_vector_type(8)));
typedef float f32x4 __attribute__((ext_vector_type(4)));

#define L2E 1.44269504088896340736f

__device__ __forceinline__ ushort f2bf(float f) {
  union { float f; uint u; } c; c.f = f;
  uint u = c.u + 0x7fffu + ((c.u >> 16) & 1u);
  return (ushort)(u >> 16);
}
__device__ __forceinline__ float bflo(uint u) { union { uint u; float f; } c; c.u = u << 16; return c.f; }
__device__ __forceinline__ float bfhi(uint u) { union { uint u; float f; } c; c.u = u & 0xffff0000u; return c.f; }

__device__ __forceinline__ void gload16(const void* g, void* l) {
  __builtin_amdgcn_global_load_lds((const __attribute__((address_space(1))) void*)g,
                                   (__attribute__((address_space(3))) void*)l, 16, 0, 0);
}

// ---------------- cast + transpose: x [B][C][4096] f32 -> xt [B][4096][C] bf16 ----------------
__global__ void cast_transpose(const float* __restrict__ x, ushort* __restrict__ xt) {
  __shared__ float t[32][33];
  const int b = blockIdx.z, pc = blockIdx.x, cc = blockIdx.y;
  const int tx = threadIdx.x, ty = threadIdx.y; // 32 x 8
  const float* xb = x + ((size_t)b * 256 + cc * 32) * 4096 + pc * 32;
#pragma unroll
  for (int i = 0; i < 4; ++i)
    t[ty * 4 + i][tx] = xb[(size_t)(ty * 4 + i) * 4096 + tx];
  __syncthreads();
  ushort* xtb = xt + ((size_t)b * 4096 + pc * 32) * 256 + cc * 32;
#pragma unroll
  for (int i = 0; i < 4; ++i)
    xtb[(size_t)(ty * 4 + i) * 256 + tx] = f2bf(t[tx][ty * 4 + i]);
}

// ---------------- elementwise f32 -> bf16 with scale ----------------
__global__ void cast_scale(const float* __restrict__ src, ushort* __restrict__ dst, int n, float scale) {
  int i = blockIdx.x * 256 + threadIdx.x;
  if (i < n) dst[i] = f2bf(src[i] * scale);
}

// ---------------- GroupNorm on pixel-major bf16 [B][4096][256], G=32 (8 ch/group) ----------------
__global__ void groupnorm(const ushort* __restrict__ y, ushort* __restrict__ gout,
                          const float* __restrict__ gamma, const float* __restrict__ beta) {
  const int g = blockIdx.x, b = blockIdx.y;
  const int tid = threadIdx.x; // 256
  const size_t base = ((size_t)b * 4096) * 256 + g * 8;
  float s = 0.f, ss = 0.f;
#pragma unroll
  for (int i = 0; i < 16; ++i) {
    int p = i * 256 + tid;
    uint4 raw = *(const uint4*)(y + base + (size_t)p * 256);
    float v0 = bflo(raw.x), v1 = bfhi(raw.x), v2 = bflo(raw.y), v3 = bfhi(raw.y);
    float v4 = bflo(raw.z), v5 = bfhi(raw.z), v6 = bflo(raw.w), v7 = bfhi(raw.w);
    s += v0 + v1 + v2 + v3 + v4 + v5 + v6 + v7;
    ss += v0 * v0 + v1 * v1 + v2 * v2 + v3 * v3 + v4 * v4 + v5 * v5 + v6 * v6 + v7 * v7;
  }
#pragma unroll
  for (int off = 1; off < 64; off <<= 1) { s += __shfl_xor(s, off); ss += __shfl_xor(ss, off); }
  __shared__ float red[10];
  if ((tid & 63) == 0) { red[tid >> 6] = s; red[4 + (tid >> 6)] = ss; }
  __syncthreads();
  if (tid == 0) {
    float S = red[0] + red[1] + red[2] + red[3];
    float SS = red[4] + red[5] + red[6] + red[7];
    float mu = S * (1.f / 32768.f);
    float var = SS * (1.f / 32768.f) - mu * mu;
    red[8] = mu; red[9] = rsqrtf(var + 1e-5f);
  }
  __syncthreads();
  const float mu = red[8], rstd = red[9];
  float ga[8], be[8];
#pragma unroll
  for (int j = 0; j < 8; ++j) { ga[j] = gamma[g * 8 + j]; be[j] = beta[g * 8 + j]; }
#pragma unroll
  for (int i = 0; i < 16; ++i) {
    int p = i * 256 + tid;
    const size_t off = base + (size_t)p * 256;
    uint4 raw = *(const uint4*)(y + off);
    float v[8] = { bflo(raw.x), bfhi(raw.x), bflo(raw.y), bfhi(raw.y),
                   bflo(raw.z), bfhi(raw.z), bflo(raw.w), bfhi(raw.w) };
    ushort o[8];
#pragma unroll
    for (int j = 0; j < 8; ++j) o[j] = f2bf((v[j] - mu) * rstd * ga[j] + be[j]);
    uint4 w;
    w.x = (uint)o[0] | ((uint)o[1] << 16); w.y = (uint)o[2] | ((uint)o[3] << 16);
    w.z = (uint)o[4] | ((uint)o[5] << 16); w.w = (uint)o[6] | ((uint)o[7] << 16);
    *(uint4*)(gout + off) = w;
  }
}

// ---------------- GEMM: D[p][o] = sum_c A[b][p][c] * W[o][c] (+bias), optional 2nd pair ----------------
// LDS tiles XOR-swizzled (128B rows): elem ^= (row&7)<<3, applied on global source + swizzled read.
__launch_bounds__(256)
__global__ void gemm_bt(const ushort* __restrict__ A, const ushort* __restrict__ A2,
                        const ushort* __restrict__ W, const ushort* __restrict__ W2,
                        const float* __restrict__ bias, const float* __restrict__ bias2,
                        ushort* __restrict__ out_pm, int pm_stride,
                        ushort* __restrict__ out_cm, float* __restrict__ out_f32,
                        int Cout, int split) {
  __shared__ ushort a_lds[128 * 64];
  __shared__ ushort b_lds[64 * 64];
  const int b = blockIdx.z;
  const int m0 = blockIdx.y * 128;
  const int n0 = blockIdx.x * 64;
  const int tid = threadIdx.x;
  const int w = tid >> 6, l = tid & 63;
  const int wr = w >> 1, wc = w & 1;
  const int lr = l & 15, lg = l >> 4;

  f32x4 acc[4][2] = {};
  const int npass = A2 ? 2 : 1;
  for (int pass = 0; pass < npass; ++pass) {
    const ushort* Ap = (pass ? A2 : A) + (size_t)b * 4096 * 256;
    const ushort* Wp = (pass ? W2 : W);
    for (int ko = 0; ko < 256; ko += 64) {
      __syncthreads();
      // stage A tile [128][64] — source pre-swizzled
#pragma unroll
      for (int j = 0; j < 4; ++j) {
        int cb = (j * 4 + w) * 64;
        int chunk = cb + l;
        int row = chunk >> 3, slot = chunk & 7;
        int col = (slot * 8) ^ ((row & 7) << 3);
        gload16(Ap + (size_t)(m0 + row) * 256 + ko + col, &a_lds[cb * 8]);
      }
      // stage Bt tile [64][64]
#pragma unroll
      for (int j = 0; j < 2; ++j) {
        int cb = (j * 4 + w) * 64;
        int chunk = cb + l;
        int row = chunk >> 3, slot = chunk & 7;
        int col = (slot * 8) ^ ((row & 7) << 3);
        gload16(Wp + (size_t)(n0 + row) * 256 + ko + col, &b_lds[cb * 8]);
      }
      __syncthreads();
#pragma unroll
      for (int kk = 0; kk < 2; ++kk) {
        bf16x8 af[4], bfr[2];
#pragma unroll
        for (int m = 0; m < 4; ++m)
          af[m] = *(const bf16x8*)&a_lds[(wr * 64 + m * 16 + lr) * 64 + ((kk * 32 + lg * 8) ^ ((lr & 7) << 3))];
#pragma unroll
        for (int n = 0; n < 2; ++n)
          bfr[n] = *(const bf16x8*)&b_lds[(wc * 32 + n * 16 + lr) * 64 + ((kk * 32 + lg * 8) ^ ((lr & 7) << 3))];
#pragma unroll
        for (int m = 0; m < 4; ++m)
#pragma unroll
          for (int n = 0; n < 2; ++n)
            acc[m][n] = __builtin_amdgcn_mfma_f32_16x16x32_bf16(af[m], bfr[n], acc[m][n], 0, 0, 0);
      }
    }
  }
#pragma unroll
  for (int n = 0; n < 2; ++n) {
    int o = n0 + wc * 32 + n * 16 + lr;
    float bv = 0.f;
    if (bias) bv += bias[o];
    if (bias2) bv += bias2[o];
#pragma unroll
    for (int m = 0; m < 4; ++m) {
      int p0 = m0 + wr * 64 + m * 16 + lg * 4;
      f32x4 v = acc[m][n];
#pragma unroll
      for (int r = 0; r < 4; ++r) {
        float val = v[r] + bv;
        int p = p0 + r;
        if (out_pm && o < split) out_pm[((size_t)b * 4096 + p) * pm_stride + o] = f2bf(val);
        if (out_cm && o >= split) out_cm[((size_t)b * (Cout - split) + (o - split)) * 4096 + p] = f2bf(val);
        if (out_f32) out_f32[((size_t)b * Cout + o) * 4096 + p] = val;
      }
    }
  }
}

// ---------------- flash attention ----------------
// Q [B][4096][256] (pre-scaled), K [B][4096][256], V [B][256][4096] -> O [B][4096][256] bf16.
// Q-tile 64 (wave w owns 16 q rows), K-tile 64. Q in registers; K/V double-buffered in LDS,
// 2-phase schedule (stage next tile before computing current). All tiles XOR-swizzled:
// K/Q (512B rows): elem ^= (row&15)<<4 ; V/P (128B rows): elem ^= (row&7)<<3.
__launch_bounds__(256)
__global__ void attn(const ushort* __restrict__ Q, const ushort* __restrict__ K,
                     const ushort* __restrict__ V, ushort* __restrict__ O) {
  __shared__ ushort kb[2][64 * 256];
  __shared__ ushort vb[2][256 * 64];
  __shared__ ushort p_lds[64 * 64];
  const int b = blockIdx.y, qt = blockIdx.x;
  const int tid = threadIdx.x;
  const int w = tid >> 6, l = tid & 63;
  const int lr = l & 15, lg = l >> 4;

  const ushort* Qb = Q + (size_t)b * 4096 * 256;
  const ushort* Kb = K + (size_t)b * 4096 * 256;
  const ushort* Vb = V + (size_t)b * 256 * 4096;

  auto stageK = [&](int kt, ushort* dst) {
#pragma unroll
    for (int j = 0; j < 8; ++j) {
      int cb = (j * 4 + w) * 64;
      int chunk = cb + l;
      int row = chunk >> 5, slot = chunk & 31;
      int col = (slot * 8) ^ ((row & 15) << 4);
      gload16(Kb + (size_t)(kt * 64 + row) * 256 + col, dst + (size_t)cb * 8);
    }
  };
  auto stageV = [&](int kt, ushort* dst) {
#pragma unroll
    for (int j = 0; j < 8; ++j) {
      int cb = (j * 4 + w) * 64;
      int chunk = cb + l;
      int row = chunk >> 3, slot = chunk & 7;
      int col = (slot * 8) ^ ((row & 7) << 3);
      gload16(Vb + (size_t)row * 4096 + kt * 64 + col, dst + (size_t)cb * 8);
    }
  };

  // stage Q tile [64][256] into kb[1], then pull this wave's fragments to registers
#pragma unroll
  for (int j = 0; j < 8; ++j) {
    int cb = (j * 4 + w) * 64;
    int chunk = cb + l;
    int row = chunk >> 5, slot = chunk & 31;
    int col = (slot * 8) ^ ((row & 15) << 4);
    gload16(Qb + (size_t)(qt * 64 + row) * 256 + col, &kb[1][cb * 8]);
  }
  __syncthreads();
  bf16x8 qf[8];
#pragma unroll
  for (int kk = 0; kk < 8; ++kk)
    qf[kk] = *(const bf16x8*)&kb[1][(w * 16 + lr) * 256 + ((kk * 32 + lg * 8) ^ (lr << 4))];

  // prologue: stage K0/V0 (does not touch kb[1])
  stageK(0, kb[0]);
  stageV(0, vb[0]);
  __syncthreads();

  float mrow[4], lsum[4];
#pragma unroll
  for (int r = 0; r < 4; ++r) { mrow[r] = -1e30f; lsum[r] = 0.f; }
  f32x4 oacc[16] = {};

  for (int kt = 0; kt < 64; ++kt) {
    const int cur = kt & 1;
    // issue next tile's async loads BEFORE compute — latency hides under MFMA+softmax
    if (kt + 1 < 64) {
      stageK(kt + 1, kb[cur ^ 1]);
      stageV(kt + 1, vb[cur ^ 1]);
    }
    const ushort* kl = kb[cur];
    const ushort* vl = vb[cur];

    // S = Q * K^T for this wave's 16 q rows x 64 k cols
    f32x4 s[4] = {};
#pragma unroll
    for (int kk = 0; kk < 8; ++kk) {
#pragma unroll
      for (int n = 0; n < 4; ++n) {
        bf16x8 bbv = *(const bf16x8*)&kl[(n * 16 + lr) * 256 + ((kk * 32 + lg * 8) ^ (lr << 4))];
        s[n] = __builtin_amdgcn_mfma_f32_16x16x32_bf16(qf[kk], bbv, s[n], 0, 0, 0);
      }
    }

    // online softmax
    float p[4][4];
#pragma unroll
    for (int r = 0; r < 4; ++r) {
      float tm = fmaxf(fmaxf(s[0][r], s[1][r]), fmaxf(s[2][r], s[3][r]));
      tm = fmaxf(tm, __shfl_xor(tm, 1, 16));
      tm = fmaxf(tm, __shfl_xor(tm, 2, 16));
      tm = fmaxf(tm, __shfl_xor(tm, 4, 16));
      tm = fmaxf(tm, __shfl_xor(tm, 8, 16));
      float mn = fmaxf(mrow[r], tm);
      float alpha = exp2f((mrow[r] - mn) * L2E);
      float rs = 0.f;
#pragma unroll
      for (int n = 0; n < 4; ++n) { p[n][r] = exp2f((s[n][r] - mn) * L2E); rs += p[n][r]; }
      rs += __shfl_xor(rs, 1, 16);
      rs += __shfl_xor(rs, 2, 16);
      rs += __shfl_xor(rs, 4, 16);
      rs += __shfl_xor(rs, 8, 16);
      lsum[r] = lsum[r] * alpha + rs;
      mrow[r] = mn;
#pragma unroll
      for (int nf = 0; nf < 16; ++nf) oacc[nf][r] *= alpha;
    }
    // P -> LDS (per-wave slice), swizzled write (C/D layout -> A layout bounce)
#pragma unroll
    for (int n = 0; n < 4; ++n)
#pragma unroll
      for (int r = 0; r < 4; ++r) {
        int prow = w * 16 + lg * 4 + r;
        p_lds[prow * 64 + ((n * 16 + lr) ^ ((prow & 7) << 3))] = f2bf(p[n][r]);
      }

    // O += P * V (swizzled reads)
#pragma unroll
    for (int ks = 0; ks < 2; ++ks) {
      bf16x8 pa = *(const bf16x8*)&p_lds[(w * 16 + lr) * 64 + ((ks * 32 + lg * 8) ^ ((lr & 7) << 3))];
#pragma unroll
      for (int nf = 0; nf < 16; ++nf) {
        bf16x8 vv = *(const bf16x8*)&vl[(nf * 16 + lr) * 64 + ((ks * 32 + lg * 8) ^ ((lr & 7) << 3))];
        oacc[nf] = __builtin_amdgcn_mfma_f32_16x16x32_bf16(pa, vv, oacc[nf], 0, 0, 0);
      }
    }
    __syncthreads();
  }

  ushort* Ob = O + (size_t)b * 4096 * 256;
#pragma unroll
  for (int nf = 0; nf < 16; ++nf) {
#pragma unroll
    for (int r = 0; r < 4; ++r) {
      int qp = qt * 64 + w * 16 + lg * 4 + r;
      Ob[(size_t)qp * 256 + nf * 16 + lr] = f2bf(oacc[nf][r] / lsum[r]);
    }
  }
}

extern "C" void kernel_launch(void* const* d_in, const int* in_sizes, int n_in,
                              void* d_out, int out_size, void* d_ws, size_t ws_size,
                              hipStream_t stream) {
  const float* x1 = (const float*)d_in[0];
  const float* x2 = (const float*)d_in[1];
  const float* w1 = (const float*)d_in[2];
  const float* b1 = (const float*)d_in[3];
  const float* w2 = (const float*)d_in[4];
  const float* b2 = (const float*)d_in[5];
  const float* gn_w = (const float*)d_in[6];
  const float* gn_b = (const float*)d_in[7];
  const float* wqkv = (const float*)d_in[8];
  const float* wout = (const float*)d_in[9];
  const float* bout = (const float*)d_in[10];
  const float* wsk = (const float*)d_in[11];
  const float* bsk = (const float*)d_in[12];
  float* out = (float*)d_out;

  const size_t NB = (size_t)4 * 4096 * 256; // elems per big bf16 buffer
  ushort* x1t = (ushort*)d_ws;      // later reused as q1t
  ushort* x2t = x1t + NB;           // later reused as k2t
  ushort* y1t = x2t + NB;           // persists (skip input)
  ushort* y2t = y1t + NB;           // GN'd in place -> g2t
  ushort* g1t = y2t + NB;           // later reused as ot
  ushort* v2  = g1t + NB;
  ushort* w1b = v2 + NB;
  ushort* w2b = w1b + 65536;
  ushort* wqb = w2b + 65536;
  ushort* wkvb = wqb + 65536;       // 131072
  ushort* woutb = wkvb + 131072;
  ushort* wskb = woutb + 65536;

  dim3 tb(32, 8);
  cast_transpose<<<dim3(128, 8, 4), tb, 0, stream>>>(x1, x1t);
  cast_transpose<<<dim3(128, 8, 4), tb, 0, stream>>>(x2, x2t);
  cast_scale<<<256, 256, 0, stream>>>(w1, w1b, 65536, 1.f);
  cast_scale<<<256, 256, 0, stream>>>(w2, w2b, 65536, 1.f);
  cast_scale<<<256, 256, 0, stream>>>(wqkv, wqb, 65536, 0.0625f); // fold 1/sqrt(256)
  cast_scale<<<512, 256, 0, stream>>>(wqkv + 65536, wkvb, 131072, 1.f);
  cast_scale<<<256, 256, 0, stream>>>(wout, woutb, 65536, 1.f);
  cast_scale<<<256, 256, 0, stream>>>(wsk, wskb, 65536, 1.f);

  // x1 = conv(x1,w1)+b1 ; x2 = conv(x2,w2)+b2
  gemm_bt<<<dim3(4, 32, 4), 256, 0, stream>>>(x1t, nullptr, w1b, nullptr, b1, nullptr,
                                              y1t, 256, nullptr, nullptr, 256, 256);
  gemm_bt<<<dim3(4, 32, 4), 256, 0, stream>>>(x2t, nullptr, w2b, nullptr, b2, nullptr,
                                              y2t, 256, nullptr, nullptr, 256, 256);
  // group norms (second one in place)
  groupnorm<<<dim3(32, 4), 256, 0, stream>>>(y1t, g1t, gn_w, gn_b);
  groupnorm<<<dim3(32, 4), 256, 0, stream>>>(y2t, y2t, gn_w, gn_b);
  // q1 = g1 @ wq^T (pre-scaled) ; [k2|v2] = g2 @ wkv^T
  gemm_bt<<<dim3(4, 32, 4), 256, 0, stream>>>(g1t, nullptr, wqb, nullptr, nullptr, nullptr,
                                              x1t, 256, nullptr, nullptr, 256, 256);
  gemm_bt<<<dim3(8, 32, 4), 256, 0, stream>>>(y2t, nullptr, wkvb, nullptr, nullptr, nullptr,
                                              x2t, 256, v2, nullptr, 512, 256);
  // attention
  attn<<<dim3(64, 4), 256, 0, stream>>>(x1t, x2t, v2, g1t);
  // out = ot @ wout^T + bout + y1 @ wsk^T + bsk  (fp32 channel-major to d_out)
  gemm_bt<<<dim3(4, 32, 4), 256, 0, stream>>>(g1t, y1t, woutb, wskb, bout, bsk,
                                              nullptr, 0, nullptr, out, 256, 0);
}

// Round 3
// 303.018 us; speedup vs baseline: 1.6273x; 1.2034x over previous
//
#include <hip/hip_runtime.h>

typedef unsigned int uint;
typedef unsigned short ushort;
typedef __bf16 bf16x8 __attribute__((ext_vector_type(8)));
typedef float f32x4 __attribute__((ext_vector_type(4)));

__device__ __forceinline__ ushort f2bf(float f) {
  union { float f; uint u; } c; c.f = f;
  uint u = c.u + 0x7fffu + ((c.u >> 16) & 1u);
  return (ushort)(u >> 16);
}
__device__ __forceinline__ float bflo(uint u) { union { uint u; float f; } c; c.u = u << 16; return c.f; }
__device__ __forceinline__ float bfhi(uint u) { union { uint u; float f; } c; c.u = u & 0xffff0000u; return c.f; }

__device__ __forceinline__ void gload16(const void* g, void* l) {
  __builtin_amdgcn_global_load_lds((const __attribute__((address_space(1))) void*)g,
                                   (__attribute__((address_space(3))) void*)l, 16, 0, 0);
}

// ---------------- cast + transpose: x [B][C][4096] f32 -> xt [B][4096][C] bf16 (both tensors) ----------------
__global__ void cast_transpose(const float* __restrict__ x1, const float* __restrict__ x2,
                               ushort* __restrict__ x1t, ushort* __restrict__ x2t) {
  __shared__ float t[32][33];
  const int z = blockIdx.z, b = z & 3, tn = z >> 2;
  const float* x = tn ? x2 : x1;
  ushort* xt = tn ? x2t : x1t;
  const int pc = blockIdx.x, cc = blockIdx.y;
  const int tx = threadIdx.x, ty = threadIdx.y; // 32 x 8
  const float* xb = x + ((size_t)b * 256 + cc * 32) * 4096 + pc * 32;
#pragma unroll
  for (int i = 0; i < 4; ++i)
    t[ty * 4 + i][tx] = xb[(size_t)(ty * 4 + i) * 4096 + tx];
  __syncthreads();
  ushort* xtb = xt + ((size_t)b * 4096 + pc * 32) * 256 + cc * 32;
#pragma unroll
  for (int i = 0; i < 4; ++i)
    xtb[(size_t)(ty * 4 + i) * 256 + tx] = f2bf(t[tx][ty * 4 + i]);
}

// ---------------- all weights -> bf16, one kernel. Q weights get 1/sqrt(C) * log2(e) folded in. ----------------
__global__ void cast_weights(const float* __restrict__ w1, const float* __restrict__ w2,
                             const float* __restrict__ wqkv, const float* __restrict__ wout,
                             const float* __restrict__ wsk,
                             ushort* __restrict__ w1b, ushort* __restrict__ w2b,
                             ushort* __restrict__ wqb, ushort* __restrict__ wkvb,
                             ushort* __restrict__ woutb, ushort* __restrict__ wskb) {
  const int i = blockIdx.x * 256 + threadIdx.x;
  const float QS = 0.0625f * 1.44269504088896f; // 1/sqrt(256) * log2(e)
  if (i < 65536) w1b[i] = f2bf(w1[i]);
  else if (i < 131072) w2b[i - 65536] = f2bf(w2[i - 65536]);
  else if (i < 196608) wqb[i - 131072] = f2bf(wqkv[i - 131072] * QS);
  else if (i < 327680) wkvb[i - 196608] = f2bf(wqkv[i - 131072]);
  else if (i < 393216) woutb[i - 327680] = f2bf(wout[i - 327680]);
  else wskb[i - 393216] = f2bf(wsk[i - 393216]);
}

// ---------------- GroupNorm on pixel-major bf16 [B][4096][256], G=32 (8 ch/group); z selects tensor ----------------
__global__ void groupnorm(const ushort* __restrict__ y1, ushort* __restrict__ o1,
                          const ushort* __restrict__ y2, /* o2 == y2 (in place) */
                          const float* __restrict__ gamma, const float* __restrict__ beta) {
  const int g = blockIdx.x, b = blockIdx.y, tn = blockIdx.z;
  const ushort* y = tn ? y2 : y1;
  ushort* gout = tn ? (ushort*)y2 : o1;
  const int tid = threadIdx.x; // 256
  const size_t base = ((size_t)b * 4096) * 256 + g * 8;
  float s = 0.f, ss = 0.f;
#pragma unroll
  for (int i = 0; i < 16; ++i) {
    int p = i * 256 + tid;
    uint4 raw = *(const uint4*)(y + base + (size_t)p * 256);
    float v0 = bflo(raw.x), v1 = bfhi(raw.x), v2 = bflo(raw.y), v3 = bfhi(raw.y);
    float v4 = bflo(raw.z), v5 = bfhi(raw.z), v6 = bflo(raw.w), v7 = bfhi(raw.w);
    s += v0 + v1 + v2 + v3 + v4 + v5 + v6 + v7;
    ss += v0 * v0 + v1 * v1 + v2 * v2 + v3 * v3 + v4 * v4 + v5 * v5 + v6 * v6 + v7 * v7;
  }
#pragma unroll
  for (int off = 1; off < 64; off <<= 1) { s += __shfl_xor(s, off); ss += __shfl_xor(ss, off); }
  __shared__ float red[10];
  if ((tid & 63) == 0) { red[tid >> 6] = s; red[4 + (tid >> 6)] = ss; }
  __syncthreads();
  if (tid == 0) {
    float S = red[0] + red[1] + red[2] + red[3];
    float SS = red[4] + red[5] + red[6] + red[7];
    float mu = S * (1.f / 32768.f);
    float var = SS * (1.f / 32768.f) - mu * mu;
    red[8] = mu; red[9] = rsqrtf(var + 1e-5f);
  }
  __syncthreads();
  const float mu = red[8], rstd = red[9];
  float ga[8], be[8];
#pragma unroll
  for (int j = 0; j < 8; ++j) { ga[j] = gamma[g * 8 + j]; be[j] = beta[g * 8 + j]; }
#pragma unroll
  for (int i = 0; i < 16; ++i) {
    int p = i * 256 + tid;
    const size_t off = base + (size_t)p * 256;
    uint4 raw = *(const uint4*)(y + off);
    float v[8] = { bflo(raw.x), bfhi(raw.x), bflo(raw.y), bfhi(raw.y),
                   bflo(raw.z), bfhi(raw.z), bflo(raw.w), bfhi(raw.w) };
    ushort o[8];
#pragma unroll
    for (int j = 0; j < 8; ++j) o[j] = f2bf((v[j] - mu) * rstd * ga[j] + be[j]);
    uint4 w;
    w.x = (uint)o[0] | ((uint)o[1] << 16); w.y = (uint)o[2] | ((uint)o[3] << 16);
    w.z = (uint)o[4] | ((uint)o[5] << 16); w.w = (uint)o[6] | ((uint)o[7] << 16);
    *(uint4*)(gout + off) = w;
  }
}

// ---------------- GEMM 128x128 tile: D[p][o] = sum_c A[b][p][c] * W[o][c] (+bias), optional 2nd pair ----------------
// LDS tiles XOR-swizzled (128B rows): elem ^= (row&7)<<3, applied on global source + swizzled read.
__launch_bounds__(256)
__global__ void gemm_bt(const ushort* __restrict__ A, const ushort* __restrict__ A2,
                        const ushort* __restrict__ W, const ushort* __restrict__ W2,
                        const float* __restrict__ bias, const float* __restrict__ bias2,
                        ushort* __restrict__ out_pm, int pm_stride,
                        ushort* __restrict__ out_cm, float* __restrict__ out_f32,
                        int Cout, int split) {
  __shared__ ushort a_lds[128 * 64];
  __shared__ ushort b_lds[128 * 64];
  const int b = blockIdx.z;
  const int m0 = blockIdx.y * 128;
  const int n0 = blockIdx.x * 128;
  const int tid = threadIdx.x;
  const int w = tid >> 6, l = tid & 63;
  const int wr = w >> 1, wc = w & 1;
  const int lr = l & 15, lg = l >> 4;

  f32x4 acc[4][4] = {};
  const int npass = A2 ? 2 : 1;
  for (int pass = 0; pass < npass; ++pass) {
    const ushort* Ap = (pass ? A2 : A) + (size_t)b * 4096 * 256;
    const ushort* Wp = (pass ? W2 : W);
    for (int ko = 0; ko < 256; ko += 64) {
      __syncthreads();
#pragma unroll
      for (int j = 0; j < 4; ++j) {
        int cb = (j * 4 + w) * 64;
        int chunk = cb + l;
        int row = chunk >> 3, slot = chunk & 7;
        int col = (slot * 8) ^ ((row & 7) << 3);
        gload16(Ap + (size_t)(m0 + row) * 256 + ko + col, &a_lds[cb * 8]);
      }
#pragma unroll
      for (int j = 0; j < 4; ++j) {
        int cb = (j * 4 + w) * 64;
        int chunk = cb + l;
        int row = chunk >> 3, slot = chunk & 7;
        int col = (slot * 8) ^ ((row & 7) << 3);
        gload16(Wp + (size_t)(n0 + row) * 256 + ko + col, &b_lds[cb * 8]);
      }
      __syncthreads();
#pragma unroll
      for (int kk = 0; kk < 2; ++kk) {
        bf16x8 af[4], bfr[4];
#pragma unroll
        for (int m = 0; m < 4; ++m)
          af[m] = *(const bf16x8*)&a_lds[(wr * 64 + m * 16 + lr) * 64 + ((kk * 32 + lg * 8) ^ ((lr & 7) << 3))];
#pragma unroll
        for (int n = 0; n < 4; ++n)
          bfr[n] = *(const bf16x8*)&b_lds[(wc * 64 + n * 16 + lr) * 64 + ((kk * 32 + lg * 8) ^ ((lr & 7) << 3))];
#pragma unroll
        for (int m = 0; m < 4; ++m)
#pragma unroll
          for (int n = 0; n < 4; ++n)
            acc[m][n] = __builtin_amdgcn_mfma_f32_16x16x32_bf16(af[m], bfr[n], acc[m][n], 0, 0, 0);
      }
    }
  }
#pragma unroll
  for (int n = 0; n < 4; ++n) {
    int o = n0 + wc * 64 + n * 16 + lr;
    float bv = 0.f;
    if (bias) bv += bias[o];
    if (bias2) bv += bias2[o];
#pragma unroll
    for (int m = 0; m < 4; ++m) {
      int p0 = m0 + wr * 64 + m * 16 + lg * 4;
      f32x4 v = acc[m][n];
#pragma unroll
      for (int r = 0; r < 4; ++r) {
        float val = v[r] + bv;
        int p = p0 + r;
        if (out_pm && o < split) out_pm[((size_t)b * 4096 + p) * pm_stride + o] = f2bf(val);
        if (out_cm && o >= split) out_cm[((size_t)b * (Cout - split) + (o - split)) * 4096 + p] = f2bf(val);
        if (out_f32) out_f32[((size_t)b * Cout + o) * 4096 + p] = val;
      }
    }
  }
}

// ---------------- flash attention, swapped-QK^T in-register softmax ----------------
// Q [B][4096][256] (pre-scaled by 1/sqrt(C)*log2e), K [B][4096][256], V [B][256][4096] -> O bf16 pixel-major.
// Grid: 256 blocks 1-D, batch-affine XCD remap (2 XCDs per batch -> per-XCD L2 working set = 1 batch K+V = 4MB).
// QK^T computed swapped: mfma(K,Q) -> lane holds S[k = n*16+lg*4+r][q = w*16+lr]; softmax row (fixed q) is
// lane-local in k except a 2-shfl max reduce; row-sum kept as lane-local partial, reduced once at the end.
// Defer-max (T13): rescale only when tile max exceeds running max by >11.5 (exp2 space).
__launch_bounds__(256)
__global__ void attn(const ushort* __restrict__ Q, const ushort* __restrict__ K,
                     const ushort* __restrict__ V, ushort* __restrict__ O) {
  __shared__ ushort kb[2][64 * 256];
  __shared__ ushort vb[2][256 * 64];
  __shared__ ushort p_lds[64 * 64];
  const int bid = blockIdx.x;
  const int xcd = bid & 7, slot = bid >> 3;
  const int b = xcd >> 1;
  const int qt = (xcd & 1) * 32 + slot;
  const int tid = threadIdx.x;
  const int w = tid >> 6, l = tid & 63;
  const int lr = l & 15, lg = l >> 4;

  const ushort* Qb = Q + (size_t)b * 4096 * 256;
  const ushort* Kb = K + (size_t)b * 4096 * 256;
  const ushort* Vb = V + (size_t)b * 256 * 4096;

  auto stageK = [&](int kt, ushort* dst) {
#pragma unroll
    for (int j = 0; j < 8; ++j) {
      int cb = (j * 4 + w) * 64;
      int chunk = cb + l;
      int row = chunk >> 5, sl = chunk & 31;
      int col = (sl * 8) ^ ((row & 15) << 4);
      gload16(Kb + (size_t)(kt * 64 + row) * 256 + col, dst + (size_t)cb * 8);
    }
  };
  auto stageV = [&](int kt, ushort* dst) {
#pragma unroll
    for (int j = 0; j < 8; ++j) {
      int cb = (j * 4 + w) * 64;
      int chunk = cb + l;
      int row = chunk >> 3, sl = chunk & 7;
      int col = (sl * 8) ^ ((row & 7) << 3);
      gload16(Vb + (size_t)row * 4096 + kt * 64 + col, dst + (size_t)cb * 8);
    }
  };

  // stage Q tile [64][256] into kb[1] as a bounce, pull this wave's fragments to registers
#pragma unroll
  for (int j = 0; j < 8; ++j) {
    int cb = (j * 4 + w) * 64;
    int chunk = cb + l;
    int row = chunk >> 5, sl = chunk & 31;
    int col = (sl * 8) ^ ((row & 15) << 4);
    gload16(Qb + (size_t)(qt * 64 + row) * 256 + col, &kb[1][cb * 8]);
  }
  __syncthreads();
  bf16x8 qf[8];
#pragma unroll
  for (int kk = 0; kk < 8; ++kk)
    qf[kk] = *(const bf16x8*)&kb[1][(w * 16 + lr) * 256 + ((kk * 32 + lg * 8) ^ (lr << 4))];

  stageK(0, kb[0]);
  stageV(0, vb[0]);
  __syncthreads();

  float mrow = -1e30f, lsum = 0.f;
  f32x4 oacc[16] = {};

  for (int kt = 0; kt < 64; ++kt) {
    const int cur = kt & 1;
    if (kt + 1 < 64) {
      stageK(kt + 1, kb[cur ^ 1]);
      stageV(kt + 1, vb[cur ^ 1]);
    }
    const ushort* kl = kb[cur];
    const ushort* vl = vb[cur];

    // S^T: lane holds S[k = n*16+lg*4+r][q = w*16+lr]  (swapped operands)
    f32x4 s[4] = {};
#pragma unroll
    for (int kk = 0; kk < 8; ++kk) {
#pragma unroll
      for (int n = 0; n < 4; ++n) {
        bf16x8 kv = *(const bf16x8*)&kl[(n * 16 + lr) * 256 + ((kk * 32 + lg * 8) ^ (lr << 4))];
        s[n] = __builtin_amdgcn_mfma_f32_16x16x32_bf16(kv, qf[kk], s[n], 0, 0, 0);
      }
    }

    // tile max for this lane's q-row (16 own values + 2 shfl across lg groups)
    float tm = fmaxf(fmaxf(fmaxf(s[0][0], s[0][1]), fmaxf(s[0][2], s[0][3])),
                     fmaxf(fmaxf(s[1][0], s[1][1]), fmaxf(s[1][2], s[1][3])));
    tm = fmaxf(tm, fmaxf(fmaxf(fmaxf(s[2][0], s[2][1]), fmaxf(s[2][2], s[2][3])),
                         fmaxf(fmaxf(s[3][0], s[3][1]), fmaxf(s[3][2], s[3][3]))));
    tm = fmaxf(tm, __shfl_xor(tm, 16));
    tm = fmaxf(tm, __shfl_xor(tm, 32));

    if (__any(tm > mrow + 11.5f)) { // defer-max: exp2 headroom 2^11.5
      float mn = fmaxf(mrow, tm);
      float alpha = exp2f(mrow - mn);
      mrow = mn;
      lsum *= alpha;
      float ar[4];
#pragma unroll
      for (int r = 0; r < 4; ++r) ar[r] = __shfl(alpha, ((l >> 4) << 2) + r);
#pragma unroll
      for (int nf = 0; nf < 16; ++nf)
#pragma unroll
        for (int r = 0; r < 4; ++r) oacc[nf][r] *= ar[r];
    }

    // P = exp2(S - m), lane-local partial row-sum; pack 4 bf16 -> ds_write_b64 into p_lds[q][k] (swizzled)
    const int prow = w * 16 + lr;
    const int psw = (prow & 7) << 3;
#pragma unroll
    for (int n = 0; n < 4; ++n) {
      float p0 = exp2f(s[n][0] - mrow), p1 = exp2f(s[n][1] - mrow);
      float p2 = exp2f(s[n][2] - mrow), p3 = exp2f(s[n][3] - mrow);
      lsum += (p0 + p1) + (p2 + p3);
      uint2 pk;
      pk.x = (uint)f2bf(p0) | ((uint)f2bf(p1) << 16);
      pk.y = (uint)f2bf(p2) | ((uint)f2bf(p3) << 16);
      *(uint2*)&p_lds[prow * 64 + ((n * 16 + lg * 4) ^ psw)] = pk;
    }

    // O += P * V (reads own wave's p_lds slice; lgkm waits inserted by compiler)
#pragma unroll
    for (int ks = 0; ks < 2; ++ks) {
      bf16x8 pa = *(const bf16x8*)&p_lds[(w * 16 + lr) * 64 + ((ks * 32 + lg * 8) ^ ((lr & 7) << 3))];
#pragma unroll
      for (int nf = 0; nf < 16; ++nf) {
        bf16x8 vv = *(const bf16x8*)&vl[(nf * 16 + lr) * 64 + ((ks * 32 + lg * 8) ^ ((lr & 7) << 3))];
        oacc[nf] = __builtin_amdgcn_mfma_f32_16x16x32_bf16(pa, vv, oacc[nf], 0, 0, 0);
      }
    }
    __syncthreads();
  }

  // final row-sum reduce (partials live per lane over its k subset) and O write
  float ls = lsum;
  ls += __shfl_xor(ls, 16);
  ls += __shfl_xor(ls, 32);
  float inv[4];
#pragma unroll
  for (int r = 0; r < 4; ++r) inv[r] = 1.f / __shfl(ls, ((l >> 4) << 2) + r);

  ushort* Ob = O + (size_t)b * 4096 * 256;
#pragma unroll
  for (int nf = 0; nf < 16; ++nf) {
#pragma unroll
    for (int r = 0; r < 4; ++r) {
      int qp = qt * 64 + w * 16 + lg * 4 + r;
      Ob[(size_t)qp * 256 + nf * 16 + lr] = f2bf(oacc[nf][r] * inv[r]);
    }
  }
}

extern "C" void kernel_launch(void* const* d_in, const int* in_sizes, int n_in,
                              void* d_out, int out_size, void* d_ws, size_t ws_size,
                              hipStream_t stream) {
  const float* x1 = (const float*)d_in[0];
  const float* x2 = (const float*)d_in[1];
  const float* w1 = (const float*)d_in[2];
  const float* b1 = (const float*)d_in[3];
  const float* w2 = (const float*)d_in[4];
  const float* b2 = (const float*)d_in[5];
  const float* gn_w = (const float*)d_in[6];
  const float* gn_b = (const float*)d_in[7];
  const float* wqkv = (const float*)d_in[8];
  const float* wout = (const float*)d_in[9];
  const float* bout = (const float*)d_in[10];
  const float* wsk = (const float*)d_in[11];
  const float* bsk = (const float*)d_in[12];
  float* out = (float*)d_out;

  const size_t NB = (size_t)4 * 4096 * 256; // elems per big bf16 buffer
  ushort* x1t = (ushort*)d_ws;      // later reused as q1t
  ushort* x2t = x1t + NB;           // later reused as k2t
  ushort* y1t = x2t + NB;           // persists (skip input)
  ushort* y2t = y1t + NB;           // GN'd in place -> g2t
  ushort* g1t = y2t + NB;           // later reused as ot
  ushort* v2  = g1t + NB;
  ushort* w1b = v2 + NB;
  ushort* w2b = w1b + 65536;
  ushort* wqb = w2b + 65536;
  ushort* wkvb = wqb + 65536;       // 131072
  ushort* woutb = wkvb + 131072;
  ushort* wskb = woutb + 65536;

  cast_transpose<<<dim3(128, 8, 8), dim3(32, 8), 0, stream>>>(x1, x2, x1t, x2t);
  cast_weights<<<1792, 256, 0, stream>>>(w1, w2, wqkv, wout, wsk,
                                         w1b, w2b, wqb, wkvb, woutb, wskb);

  // x1 = conv(x1,w1)+b1 ; x2 = conv(x2,w2)+b2
  gemm_bt<<<dim3(2, 32, 4), 256, 0, stream>>>(x1t, nullptr, w1b, nullptr, b1, nullptr,
                                              y1t, 256, nullptr, nullptr, 256, 256);
  gemm_bt<<<dim3(2, 32, 4), 256, 0, stream>>>(x2t, nullptr, w2b, nullptr, b2, nullptr,
                                              y2t, 256, nullptr, nullptr, 256, 256);
  // group norms (tensor 2 in place)
  groupnorm<<<dim3(32, 4, 2), 256, 0, stream>>>(y1t, g1t, y2t, gn_w, gn_b);
  // q1 = g1 @ wq^T (pre-scaled) ; [k2|v2] = g2 @ wkv^T
  gemm_bt<<<dim3(2, 32, 4), 256, 0, stream>>>(g1t, nullptr, wqb, nullptr, nullptr, nullptr,
                                              x1t, 256, nullptr, nullptr, 256, 256);
  gemm_bt<<<dim3(4, 32, 4), 256, 0, stream>>>(y2t, nullptr, wkvb, nullptr, nullptr, nullptr,
                                              x2t, 256, v2, nullptr, 512, 256);
  // attention
  attn<<<256, 256, 0, stream>>>(x1t, x2t, v2, g1t);
  // out = ot @ wout^T + bout + y1 @ wsk^T + bsk  (fp32 channel-major to d_out)
  gemm_bt<<<dim3(2, 32, 4), 256, 0, stream>>>(g1t, y1t, woutb, wskb, bout, bsk,
                                              nullptr, 0, nullptr, out, 256, 0);
}